// Round 15
// baseline (151.680 us; speedup 1.0000x reference)
//
#include <hip/hip_runtime.h>

typedef _Float16 f16;
typedef f16 f16x8 __attribute__((ext_vector_type(8)));
typedef f16 f16x4 __attribute__((ext_vector_type(4)));
typedef float f32x4 __attribute__((ext_vector_type(4)));

#define BSZ 4
#define NH 16
#define SEQ 1024
#define DKD 64
#define QB 16
#define LOG2E 1.44269504088896340736f

#define KP_ELEMS ((size_t)BSZ * NH * SEQ * DKD)            // 4.19M f16 per tensor
#define WS_LEN_OFF  (2 * KP_ELEMS * sizeof(f16))           // len[4] after Kp,Vpk

// ---------------- prepack (champion, unchanged) ----------------
// K -> Kp[bh][s][d] f16; V -> Vpk[bh][(s>>2)*256 + dv*4 + (s&3)] f16
// block(0,0,0) also decodes key_padding_mask -> len[b].
__global__ __launch_bounds__(256, 4)
void prepack_kernel(const float* __restrict__ kg,   // [bh][64][1024]
                    const float* __restrict__ vg,   // [bh][1024][64]
                    const int*   __restrict__ kpm,
                    f16* __restrict__ wsf,
                    int* __restrict__ lenw)
{
    __shared__ float lds[64][65];
    __shared__ int smode, slen[BSZ];
    const int tid  = threadIdx.x;
    const int st   = blockIdx.x;       // 64-wide s tile
    const int bh   = blockIdx.y;
    const int task = blockIdx.z;       // 0 = K, 1 = V

    if (task == 0) {
        const float* src = kg + (size_t)bh * SEQ * DKD + (size_t)st * 64;
        f16* dst = wsf + (size_t)bh * SEQ * DKD + (size_t)st * 64 * 64;
        const int rr = tid >> 2, cb = (tid & 3) * 16;
        #pragma unroll
        for (int i = 0; i < 4; ++i) {
            f32x4 x = *(const f32x4*)(src + (size_t)rr * SEQ + cb + i * 4);
            lds[rr][cb + i * 4 + 0] = x[0];
            lds[rr][cb + i * 4 + 1] = x[1];
            lds[rr][cb + i * 4 + 2] = x[2];
            lds[rr][cb + i * 4 + 3] = x[3];
        }
        __syncthreads();
        const int c = tid >> 2, rb = (tid & 3) * 16;   // c = s_local, rb = d base
        f16 tmp[16];
        #pragma unroll
        for (int i = 0; i < 16; ++i) tmp[i] = (f16)lds[rb + i][c];
        *(f16x8*)(dst + (size_t)c * 64 + rb)     = *(f16x8*)&tmp[0];
        *(f16x8*)(dst + (size_t)c * 64 + rb + 8) = *(f16x8*)&tmp[8];
    } else {
        const float* src = vg + (size_t)bh * SEQ * DKD + (size_t)st * 64 * 64;
        f16* dst = wsf + KP_ELEMS + (size_t)bh * SEQ * DKD;
        const int rr = tid >> 2, cb = (tid & 3) * 16;
        #pragma unroll
        for (int i = 0; i < 4; ++i) {
            f32x4 x = *(const f32x4*)(src + (size_t)rr * 64 + cb + i * 4);
            lds[rr][cb + i * 4 + 0] = x[0];
            lds[rr][cb + i * 4 + 1] = x[1];
            lds[rr][cb + i * 4 + 2] = x[2];
            lds[rr][cb + i * 4 + 3] = x[3];
        }
        __syncthreads();
        const int dv = tid & 63, sq0 = tid >> 6;
        #pragma unroll
        for (int i = 0; i < 4; ++i) {
            const int sq = sq0 + 4 * i;            // s_local>>2, 0..15
            f16x4 v;
            #pragma unroll
            for (int j = 0; j < 4; ++j) v[j] = (f16)lds[sq * 4 + j][dv];
            *(f16x4*)(dst + ((size_t)(st * 16 + sq) * 256 + dv * 4)) = v;
        }
    }

    if (st == 0 && bh == 0 && task == 0) {
        if (tid < BSZ) slen[tid] = SEQ;
        if (tid == BSZ) smode = 0;
        __syncthreads();
        {
            const unsigned int* w32 = (const unsigned int*)kpm;
            int bad = 0;
            #pragma unroll
            for (int j = 0; j < 4; ++j) {
                unsigned int w = w32[tid * 4 + j];
                if (w != 0u && w != 1u && w != 0x3F800000u) bad = 1;
            }
            if (bad) atomicOr(&smode, 1);
        }
        __syncthreads();
        for (int b = 0; b < BSZ; ++b) {
            int m0 = SEQ;
            if (smode == 0) {
                const unsigned int* w32 = (const unsigned int*)kpm + b * SEQ;
                #pragma unroll
                for (int j = 0; j < 4; ++j) {
                    int i = tid * 4 + j;
                    if (w32[i] != 0u && i < m0) m0 = i;
                }
            } else {
                const unsigned char* u8 = (const unsigned char*)kpm + b * SEQ;
                #pragma unroll
                for (int j = 0; j < 4; ++j) {
                    int i = tid * 4 + j;
                    if (u8[i] != 0 && i < m0) m0 = i;
                }
            }
            if (m0 < SEQ) atomicMin(&slen[b], m0);
        }
        __syncthreads();
        if (tid < BSZ) lenw[tid] = slen[tid];
    }
}

// ---------------- zero-fill: the masked attn region [zlim(row), SEQ) ----------------
// Pure streaming stores (fill kernels hit ~6.9 TB/s on this chip). One wave per row;
// disjoint from the mono kernel's [0, zlim) stores by construction.
__global__ __launch_bounds__(256, 8)
void zfill_kernel(const int* __restrict__ lenw, float* __restrict__ out_attn)
{
    const int tid  = threadIdx.x;
    const int lane = tid & 63;
    const int R    = blockIdx.x * 4 + (tid >> 6);   // global row, 0..65535
    const int bh   = R >> 10;
    const int qrow = R & 1023;
    const int b    = bh >> 4;

    const int len  = lenw[b];
    const int q0   = qrow & ~(QB - 1);
    const int smax = min(q0 + QB, len);
    const int zlim = ((smax + 63) >> 6) * 64;       // same formula as mono kernel

    float* dst = out_attn + (size_t)R * SEQ;
    const f32x4 z = {0.f, 0.f, 0.f, 0.f};
    #pragma unroll
    for (int it = 0; it < 4; ++it) {
        const int c = it * 256 + lane * 4;
        if (c >= zlim) __builtin_nontemporal_store(z, (f32x4*)(dst + c));
    }
}

// ---------------- fused mono kernel (champion schedule; stores only active tiles) ----------------
// One block = one (b,h) x 16 q-rows; 4 waves each own a 16-key slice per 64-key tile.
// Swapped QK^T (lane = q-row) -> exp() output IS the PV A-fragment. No in-loop barrier.
// Ordered-vmcnt-aware: KV(0),KV(1) issued FIRST, then the FULL 16-tile prev burst, then
// the loop. Separate redp LDS; one barrier; ctx then attn stores LAST (active cols only —
// the zero region is written by zfill_kernel at streaming rate).
__global__ __launch_bounds__(256, 3)
void sdpa_mono_kernel(const float* __restrict__ qg,
                      const float* __restrict__ pg,   // prev [bh][1024][1024]
                      const f16*  __restrict__ wsf,   // Kp, Vpk
                      const int*  __restrict__ lenw,
                      float* __restrict__ out_ctx,    // [bh][1024][64]
                      float* __restrict__ out_attn)   // [bh][1024][1024]
{
    __shared__ __align__(16) f16 Elds[QB * SEQ];      // 32 KB
    __shared__ float redp[4 * QB * 65];               // 16.6 KB (separate: no store-drain barrier)
    __shared__ float rs_part[4][QB];
#define REDP(w, row, dv) redp[((w) * QB + (row)) * 65 + (dv)]

    const int tid  = threadIdx.x;
    const int wave = tid >> 6;
    const int lane = tid & 63;
    const int lo   = lane & 15;
    const int hi   = lane >> 4;

    // XCD swizzle (4096 % 8 == 0) + LPT (heavy q-blocks first)
    const int bid  = blockIdx.x;
    const int nid  = (bid & 7) * 512 + (bid >> 3);
    const int bh   = nid >> 6;
    const int qblk = 63 - (nid & 63);
    const int b    = bh >> 4;
    const int q0   = qblk * QB;

    const int len  = lenw[b];
    const int smax = min(q0 + QB, len);
    const int nT   = (smax + 63) >> 6;

    const size_t qkvbase = (size_t)bh * SEQ * DKD;
    const f16* kpp = wsf + qkvbase;                                        // Kp[s][d]
    const f16* vpk = wsf + KP_ELEMS + qkvbase + (wave * 4 + hi) * 256 + lo * 4;
    const float* pp = pg + (size_t)bh * SEQ * SEQ + (size_t)(q0 + lo) * SEQ + wave * 16 + hi * 4;
    const int qrow = q0 + lo;

    // Q as B-fragment (col = q-row = lo, k = d), 1/8 scale folded in (exact)
    f16x8 qb0, qb1;
    {
        const float* src = qg + qkvbase + (size_t)qrow * DKD + hi * 8;
        #pragma unroll
        for (int j = 0; j < 8; ++j) qb0[j] = (f16)(src[j] * 0.125f);
        #pragma unroll
        for (int j = 0; j < 8; ++j) qb1[j] = (f16)(src[32 + j] * 0.125f);
    }

    f32x4 accP[4] = {{0.f,0.f,0.f,0.f},{0.f,0.f,0.f,0.f},{0.f,0.f,0.f,0.f},{0.f,0.f,0.f,0.f}};
    float rsl = 0.f;

    f32x4 bP[16];        // FULL prev burst, one slot per tile (statically indexed)
    f16x8 bK0[2], bK1[2];
    f16x4 bV[2][4];

#define LOADKV(SL, T) do {                                                      \
    const int c0_ = (T) * 64 + wave * 16;                                       \
    bK0[SL] = *(const f16x8*)(kpp + (size_t)(c0_ + lo) * DKD + hi * 8);         \
    bK1[SL] = *(const f16x8*)(kpp + (size_t)(c0_ + lo) * DKD + 32 + hi * 8);    \
    bV[SL][0] = *(const f16x4*)(vpk + (T) * 4096);                              \
    bV[SL][1] = *(const f16x4*)(vpk + (T) * 4096 + 64);                         \
    bV[SL][2] = *(const f16x4*)(vpk + (T) * 4096 + 128);                        \
    bV[SL][3] = *(const f16x4*)(vpk + (T) * 4096 + 192);                        \
} while (0)

    // ---- prologue: KV(0),KV(1) first (their waits never drain the prev stream),
    //      then the full prev burst for all active tiles ----
    LOADKV(0, 0);
    if (1 < nT) LOADKV(1, 1);
    #pragma unroll
    for (int i = 0; i < 16; ++i)
        if (i < nT) bP[i] = __builtin_nontemporal_load((const f32x4*)(pp + i * 64));

    #pragma unroll
    for (int t = 0; t < 16; ++t) {
        if (t < nT) {
            const f32x4 pv = bP[t];
            f32x4 accS = {0.f, 0.f, 0.f, 0.f};
            accS = __builtin_amdgcn_mfma_f32_16x16x32_f16(bK0[t & 1], qb0, accS, 0, 0, 0);
            accS = __builtin_amdgcn_mfma_f32_16x16x32_f16(bK1[t & 1], qb1, accS, 0, 0, 0);
            const int c0_ = t * 64 + wave * 16;
            f16x4 ev;
            #pragma unroll
            for (int r = 0; r < 4; ++r) {
                const int scol = c0_ + hi * 4 + r;
                const float sc = accS[r] + pv[r];
                float e = (scol <= qrow && scol < len) ? exp2f(sc * LOG2E) : 0.f;
                rsl += e;
                ev[r] = (f16)e;
            }
            *(f16x4*)&Elds[lo * SEQ + ((c0_ + hi * 4) ^ ((lo & 7) << 3))] = ev;  // XOR-swizzled
            accP[0] = __builtin_amdgcn_mfma_f32_16x16x16f16(ev, bV[t & 1][0], accP[0], 0, 0, 0);
            accP[1] = __builtin_amdgcn_mfma_f32_16x16x16f16(ev, bV[t & 1][1], accP[1], 0, 0, 0);
            accP[2] = __builtin_amdgcn_mfma_f32_16x16x16f16(ev, bV[t & 1][2], accP[2], 0, 0, 0);
            accP[3] = __builtin_amdgcn_mfma_f32_16x16x16f16(ev, bV[t & 1][3], accP[3], 0, 0, 0);
            if (t + 2 < nT) LOADKV(t & 1, t + 2);
        }
    }
#undef LOADKV

    // ---- row-sum + ctx partials (LDS only) ----
    rsl += __shfl_xor(rsl, 16);
    rsl += __shfl_xor(rsl, 32);
    if (lane < 16) rs_part[wave][lane] = rsl;

    #pragma unroll
    for (int dvb = 0; dvb < 4; ++dvb) {
        #pragma unroll
        for (int r = 0; r < 4; ++r) REDP(wave, hi * 4 + r, dvb * 16 + lo) = accP[dvb][r];
    }
    __syncthreads();   // only LDS traffic outstanding -> cheap drain

    // ---- ctx out: 1024 elems, coalesced NT stores ----
    float* ctxp = out_ctx + qkvbase + (size_t)q0 * DKD;
    #pragma unroll
    for (int i = 0; i < 4; ++i) {
        const int f = i * 256 + tid;
        const int row = f >> 6, dv = f & 63;
        const float s = REDP(0, row, dv) + REDP(1, row, dv) + REDP(2, row, dv) + REDP(3, row, dv);
        const float inv = 1.0f / (rs_part[0][row] + rs_part[1][row] + rs_part[2][row] + rs_part[3][row]);
        __builtin_nontemporal_store(s * inv, ctxp + f);
    }

    // ---- attn out LAST: only ACTIVE cols (c < zlim); zeros handled by zfill_kernel ----
    {
        float* ap = out_attn + (size_t)bh * SEQ * SEQ + (size_t)q0 * SEQ;
        const int zlim = nT * 64;
        #pragma unroll
        for (int ro = 0; ro < 4; ++ro) {
            const int row = wave * 4 + ro;
            const float invr = 1.0f / (rs_part[0][row] + rs_part[1][row] + rs_part[2][row] + rs_part[3][row]);
            float* dst = ap + (size_t)row * SEQ;
            #pragma unroll
            for (int it = 0; it < 4; ++it) {
                const int c = it * 256 + lane * 4;
                if (c < zlim) {
                    f16x4 evv = *(const f16x4*)&Elds[row * SEQ + (c ^ ((row & 7) << 3))];
                    f32x4 o;
                    o[0] = (float)evv[0] * invr;
                    o[1] = (float)evv[1] * invr;
                    o[2] = (float)evv[2] * invr;
                    o[3] = (float)evv[3] * invr;
                    __builtin_nontemporal_store(o, (f32x4*)(dst + c));
                }
            }
        }
    }
#undef REDP
}

extern "C" void kernel_launch(void* const* d_in, const int* in_sizes, int n_in,
                              void* d_out, int out_size, void* d_ws, size_t ws_size,
                              hipStream_t stream) {
    const float* q    = (const float*)d_in[0];
    const float* k    = (const float*)d_in[1];
    const float* v    = (const float*)d_in[2];
    const float* prev = (const float*)d_in[3];
    const int*   kpm  = (const int*)d_in[5];   // d_in[4] = additive causal mask, handled analytically

    float* out_ctx  = (float*)d_out;
    float* out_attn = out_ctx + (size_t)BSZ * NH * SEQ * DKD;

    f16* wsf  = (f16*)d_ws;
    int* lenw = (int*)((char*)d_ws + WS_LEN_OFF);

    prepack_kernel<<<dim3(16, 64, 2), 256, 0, stream>>>(k, v, kpm, wsf, lenw);
    zfill_kernel<<<dim3(BSZ * NH * SEQ / 4), 256, 0, stream>>>(lenw, out_attn);
    sdpa_mono_kernel<<<dim3(64 * 64), 256, 0, stream>>>(q, prev, wsf, lenw, out_ctx, out_attn);
}

// Round 16
// 139.633 us; speedup vs baseline: 1.0863x; 1.0863x over previous
//
#include <hip/hip_runtime.h>

typedef _Float16 f16;
typedef f16 f16x8 __attribute__((ext_vector_type(8)));
typedef f16 f16x4 __attribute__((ext_vector_type(4)));
typedef float f32x4 __attribute__((ext_vector_type(4)));

#define BSZ 4
#define NH 16
#define SEQ 1024
#define DKD 64
#define QB 16
#define LOG2E 1.44269504088896340736f

#define KP_ELEMS ((size_t)BSZ * NH * SEQ * DKD)            // 4.19M f16 per tensor
#define WS_LEN_OFF  (2 * KP_ELEMS * sizeof(f16))           // len[4] after Kp,Vpk

// ---------------- prepack ----------------
// K -> Kp[bh][s][d] f16; V -> Vpk[bh][(s>>2)*256 + dv*4 + (s&3)] f16
// (per (tile,hi) the 64x4 V sub-fragment is one contiguous 512B chunk)
// block(0,0,0) also decodes key_padding_mask -> len[b].
__global__ __launch_bounds__(256, 4)
void prepack_kernel(const float* __restrict__ kg,   // [bh][64][1024]
                    const float* __restrict__ vg,   // [bh][1024][64]
                    const int*   __restrict__ kpm,
                    f16* __restrict__ wsf,
                    int* __restrict__ lenw)
{
    __shared__ float lds[64][65];
    __shared__ int smode, slen[BSZ];
    const int tid  = threadIdx.x;
    const int st   = blockIdx.x;       // 64-wide s tile
    const int bh   = blockIdx.y;
    const int task = blockIdx.z;       // 0 = K, 1 = V

    if (task == 0) {
        const float* src = kg + (size_t)bh * SEQ * DKD + (size_t)st * 64;
        f16* dst = wsf + (size_t)bh * SEQ * DKD + (size_t)st * 64 * 64;
        const int rr = tid >> 2, cb = (tid & 3) * 16;
        #pragma unroll
        for (int i = 0; i < 4; ++i) {
            f32x4 x = *(const f32x4*)(src + (size_t)rr * SEQ + cb + i * 4);
            lds[rr][cb + i * 4 + 0] = x[0];
            lds[rr][cb + i * 4 + 1] = x[1];
            lds[rr][cb + i * 4 + 2] = x[2];
            lds[rr][cb + i * 4 + 3] = x[3];
        }
        __syncthreads();
        const int c = tid >> 2, rb = (tid & 3) * 16;   // c = s_local, rb = d base
        f16 tmp[16];
        #pragma unroll
        for (int i = 0; i < 16; ++i) tmp[i] = (f16)lds[rb + i][c];
        *(f16x8*)(dst + (size_t)c * 64 + rb)     = *(f16x8*)&tmp[0];
        *(f16x8*)(dst + (size_t)c * 64 + rb + 8) = *(f16x8*)&tmp[8];
    } else {
        const float* src = vg + (size_t)bh * SEQ * DKD + (size_t)st * 64 * 64;
        f16* dst = wsf + KP_ELEMS + (size_t)bh * SEQ * DKD;
        const int rr = tid >> 2, cb = (tid & 3) * 16;
        #pragma unroll
        for (int i = 0; i < 4; ++i) {
            f32x4 x = *(const f32x4*)(src + (size_t)rr * 64 + cb + i * 4);
            lds[rr][cb + i * 4 + 0] = x[0];
            lds[rr][cb + i * 4 + 1] = x[1];
            lds[rr][cb + i * 4 + 2] = x[2];
            lds[rr][cb + i * 4 + 3] = x[3];
        }
        __syncthreads();
        const int dv = tid & 63, sq0 = tid >> 6;
        #pragma unroll
        for (int i = 0; i < 4; ++i) {
            const int sq = sq0 + 4 * i;            // s_local>>2, 0..15
            f16x4 v;
            #pragma unroll
            for (int j = 0; j < 4; ++j) v[j] = (f16)lds[sq * 4 + j][dv];
            *(f16x4*)(dst + ((size_t)(st * 16 + sq) * 256 + dv * 4)) = v;
        }
    }

    if (st == 0 && bh == 0 && task == 0) {
        if (tid < BSZ) slen[tid] = SEQ;
        if (tid == BSZ) smode = 0;
        __syncthreads();
        {
            const unsigned int* w32 = (const unsigned int*)kpm;
            int bad = 0;
            #pragma unroll
            for (int j = 0; j < 4; ++j) {
                unsigned int w = w32[tid * 4 + j];
                if (w != 0u && w != 1u && w != 0x3F800000u) bad = 1;
            }
            if (bad) atomicOr(&smode, 1);
        }
        __syncthreads();
        for (int b = 0; b < BSZ; ++b) {
            int m0 = SEQ;
            if (smode == 0) {
                const unsigned int* w32 = (const unsigned int*)kpm + b * SEQ;
                #pragma unroll
                for (int j = 0; j < 4; ++j) {
                    int i = tid * 4 + j;
                    if (w32[i] != 0u && i < m0) m0 = i;
                }
            } else {
                const unsigned char* u8 = (const unsigned char*)kpm + b * SEQ;
                #pragma unroll
                for (int j = 0; j < 4; ++j) {
                    int i = tid * 4 + j;
                    if (u8[i] != 0 && i < m0) m0 = i;
                }
            }
            if (m0 < SEQ) atomicMin(&slen[b], m0);
        }
        __syncthreads();
        if (tid < BSZ) lenw[tid] = slen[tid];
    }
}

// ---------------- fused mono kernel (champion: R9/R14 config, exact) ----------------
// One block = one (b,h) x 16 q-rows; 4 waves each own a 16-key slice per 64-key tile.
// Swapped QK^T (lane = q-row) -> exp() output IS the PV A-fragment. No in-loop barrier.
// Ordered-vmcnt-aware: KV(0),KV(1) issued FIRST, then the FULL 16-tile prev burst, then
// the loop (no mid-loop prev issues -> no refill drain stalls). Separate redp LDS
// region -> single cheap barrier before any global store; attn stores are the LAST
// instructions (drain overlaps kernel end). LPT heavy-first: light blocks fill the tail.
__global__ __launch_bounds__(256, 3)
void sdpa_mono_kernel(const float* __restrict__ qg,
                      const float* __restrict__ pg,   // prev [bh][1024][1024]
                      const f16*  __restrict__ wsf,   // Kp, Vpk
                      const int*  __restrict__ lenw,
                      float* __restrict__ out_ctx,    // [bh][1024][64]
                      float* __restrict__ out_attn)   // [bh][1024][1024]
{
    __shared__ __align__(16) f16 Elds[QB * SEQ];      // 32 KB
    __shared__ float redp[4 * QB * 65];               // 16.6 KB (separate: no store-drain barrier)
    __shared__ float rs_part[4][QB];
#define REDP(w, row, dv) redp[((w) * QB + (row)) * 65 + (dv)]

    const int tid  = threadIdx.x;
    const int wave = tid >> 6;
    const int lane = tid & 63;
    const int lo   = lane & 15;
    const int hi   = lane >> 4;

    // XCD swizzle (4096 % 8 == 0) + LPT (heavy q-blocks first)
    const int bid  = blockIdx.x;
    const int nid  = (bid & 7) * 512 + (bid >> 3);
    const int bh   = nid >> 6;
    const int qblk = 63 - (nid & 63);
    const int b    = bh >> 4;
    const int q0   = qblk * QB;

    const int len  = lenw[b];
    const int smax = min(q0 + QB, len);
    const int nT   = (smax + 63) >> 6;

    const size_t qkvbase = (size_t)bh * SEQ * DKD;
    const f16* kpp = wsf + qkvbase;                                        // Kp[s][d]
    const f16* vpk = wsf + KP_ELEMS + qkvbase + (wave * 4 + hi) * 256 + lo * 4;
    const float* pp = pg + (size_t)bh * SEQ * SEQ + (size_t)(q0 + lo) * SEQ + wave * 16 + hi * 4;
    const int qrow = q0 + lo;

    // Q as B-fragment (col = q-row = lo, k = d), 1/8 scale folded in (exact)
    f16x8 qb0, qb1;
    {
        const float* src = qg + qkvbase + (size_t)qrow * DKD + hi * 8;
        #pragma unroll
        for (int j = 0; j < 8; ++j) qb0[j] = (f16)(src[j] * 0.125f);
        #pragma unroll
        for (int j = 0; j < 8; ++j) qb1[j] = (f16)(src[32 + j] * 0.125f);
    }

    f32x4 accP[4] = {{0.f,0.f,0.f,0.f},{0.f,0.f,0.f,0.f},{0.f,0.f,0.f,0.f},{0.f,0.f,0.f,0.f}};
    float rsl = 0.f;

    f32x4 bP[16];        // FULL prev burst, one slot per tile (statically indexed)
    f16x8 bK0[2], bK1[2];
    f16x4 bV[2][4];

#define LOADKV(SL, T) do {                                                      \
    const int c0_ = (T) * 64 + wave * 16;                                       \
    bK0[SL] = *(const f16x8*)(kpp + (size_t)(c0_ + lo) * DKD + hi * 8);         \
    bK1[SL] = *(const f16x8*)(kpp + (size_t)(c0_ + lo) * DKD + 32 + hi * 8);    \
    bV[SL][0] = *(const f16x4*)(vpk + (T) * 4096);                              \
    bV[SL][1] = *(const f16x4*)(vpk + (T) * 4096 + 64);                         \
    bV[SL][2] = *(const f16x4*)(vpk + (T) * 4096 + 128);                        \
    bV[SL][3] = *(const f16x4*)(vpk + (T) * 4096 + 192);                        \
} while (0)

    // ---- prologue: KV(0),KV(1) first (their waits never drain the prev stream),
    //      then the full prev burst for all active tiles ----
    LOADKV(0, 0);
    if (1 < nT) LOADKV(1, 1);
    #pragma unroll
    for (int i = 0; i < 16; ++i)
        if (i < nT) bP[i] = __builtin_nontemporal_load((const f32x4*)(pp + i * 64));

    #pragma unroll
    for (int t = 0; t < 16; ++t) {
        if (t < nT) {
            const f32x4 pv = bP[t];
            f32x4 accS = {0.f, 0.f, 0.f, 0.f};
            accS = __builtin_amdgcn_mfma_f32_16x16x32_f16(bK0[t & 1], qb0, accS, 0, 0, 0);
            accS = __builtin_amdgcn_mfma_f32_16x16x32_f16(bK1[t & 1], qb1, accS, 0, 0, 0);
            const int c0_ = t * 64 + wave * 16;
            f16x4 ev;
            #pragma unroll
            for (int r = 0; r < 4; ++r) {
                const int scol = c0_ + hi * 4 + r;
                const float sc = accS[r] + pv[r];
                float e = (scol <= qrow && scol < len) ? exp2f(sc * LOG2E) : 0.f;
                rsl += e;
                ev[r] = (f16)e;
            }
            *(f16x4*)&Elds[lo * SEQ + ((c0_ + hi * 4) ^ ((lo & 7) << 3))] = ev;  // XOR-swizzled
            accP[0] = __builtin_amdgcn_mfma_f32_16x16x16f16(ev, bV[t & 1][0], accP[0], 0, 0, 0);
            accP[1] = __builtin_amdgcn_mfma_f32_16x16x16f16(ev, bV[t & 1][1], accP[1], 0, 0, 0);
            accP[2] = __builtin_amdgcn_mfma_f32_16x16x16f16(ev, bV[t & 1][2], accP[2], 0, 0, 0);
            accP[3] = __builtin_amdgcn_mfma_f32_16x16x16f16(ev, bV[t & 1][3], accP[3], 0, 0, 0);
            if (t + 2 < nT) LOADKV(t & 1, t + 2);
        }
    }
#undef LOADKV

    // ---- row-sum + ctx partials (LDS only) ----
    rsl += __shfl_xor(rsl, 16);
    rsl += __shfl_xor(rsl, 32);
    if (lane < 16) rs_part[wave][lane] = rsl;

    #pragma unroll
    for (int dvb = 0; dvb < 4; ++dvb) {
        #pragma unroll
        for (int r = 0; r < 4; ++r) REDP(wave, hi * 4 + r, dvb * 16 + lo) = accP[dvb][r];
    }
    __syncthreads();   // only LDS traffic outstanding -> cheap drain

    // ---- ctx out: 1024 elems, coalesced NT stores ----
    float* ctxp = out_ctx + qkvbase + (size_t)q0 * DKD;
    #pragma unroll
    for (int i = 0; i < 4; ++i) {
        const int f = i * 256 + tid;
        const int row = f >> 6, dv = f & 63;
        const float s = REDP(0, row, dv) + REDP(1, row, dv) + REDP(2, row, dv) + REDP(3, row, dv);
        const float inv = 1.0f / (rs_part[0][row] + rs_part[1][row] + rs_part[2][row] + rs_part[3][row]);
        __builtin_nontemporal_store(s * inv, ctxp + f);
    }

    // ---- attn out LAST: contiguous 1KB/wave NT stores, no trailing barrier ----
    {
        float* ap = out_attn + (size_t)bh * SEQ * SEQ + (size_t)q0 * SEQ;
        const int zlim = nT * 64;
        #pragma unroll
        for (int ro = 0; ro < 4; ++ro) {
            const int row = wave * 4 + ro;
            const float invr = 1.0f / (rs_part[0][row] + rs_part[1][row] + rs_part[2][row] + rs_part[3][row]);
            float* dst = ap + (size_t)row * SEQ;
            #pragma unroll
            for (int it = 0; it < 4; ++it) {
                const int c = it * 256 + lane * 4;
                f32x4 o;
                if (c < zlim) {
                    f16x4 evv = *(const f16x4*)&Elds[row * SEQ + (c ^ ((row & 7) << 3))];
                    o[0] = (float)evv[0] * invr;
                    o[1] = (float)evv[1] * invr;
                    o[2] = (float)evv[2] * invr;
                    o[3] = (float)evv[3] * invr;
                } else {
                    o = (f32x4){0.f, 0.f, 0.f, 0.f};
                }
                __builtin_nontemporal_store(o, (f32x4*)(dst + c));
            }
        }
    }
#undef REDP
}

extern "C" void kernel_launch(void* const* d_in, const int* in_sizes, int n_in,
                              void* d_out, int out_size, void* d_ws, size_t ws_size,
                              hipStream_t stream) {
    const float* q    = (const float*)d_in[0];
    const float* k    = (const float*)d_in[1];
    const float* v    = (const float*)d_in[2];
    const float* prev = (const float*)d_in[3];
    const int*   kpm  = (const int*)d_in[5];   // d_in[4] = additive causal mask, handled analytically

    float* out_ctx  = (float*)d_out;
    float* out_attn = out_ctx + (size_t)BSZ * NH * SEQ * DKD;

    f16* wsf  = (f16*)d_ws;
    int* lenw = (int*)((char*)d_ws + WS_LEN_OFF);

    prepack_kernel<<<dim3(16, 64, 2), 256, 0, stream>>>(k, v, kpm, wsf, lenw);
    sdpa_mono_kernel<<<dim3(64 * 64), 256, 0, stream>>>(q, prev, wsf, lenw, out_ctx, out_attn);
}